// Round 26
// baseline (37.077 us; speedup 1.0000x reference)
//
#include <hip/hip_runtime.h>
#include <hip/hip_bf16.h>
#include <math.h>

// Sizes fixed by the reference: B=16, N=2048, F_in=F_out=64.
#define NB 16
#define NN 2048
#define NF 64
#define LOG2E 1.44269504f

// g(t) nearest-neighbor table: t in [T_LO, T_HI], NT bins, value at bin midpoint.
#define NT 4096
#define T_LO (-40.0f)
#define T_HI (10.0f)
#define T_SCALE (NT / (T_HI - T_LO))         // 81.92 bins per unit t
#define Z_BIAS (-T_LO * T_SCALE)             // 3276.8
#define Z_MAX ((float)(NT - 1))

// F sampling grid: 512 points over [-96, 96), step 0.375 (division-sensitive).
#define MG 512
#define XG_LO (-96.0f)
#define DXG 0.375f
#define INV_DXG (1.0f / DXG)                 // 2.666667
#define U_BIAS (-XG_LO * INV_DXG)            // 256.0
#define U_MAX 510.999f                       // clamp so k+1 <= 511

// G sampling grid: 256 points over [-96, 96), step 0.75 (double-smoothed output).
// gbuild tiles stride 15 (overlap-tiling) so each block serves buckets
// [15*ib, 15*ib+14] with both lerp rows in-tile; 17 tiles cover [0,254].
#define MGG 256
#define DXGG 0.75f
#define UG_MAX 254.999f                      // clamp so k+1 <= 255
#define GS_N 1024
#define TILES 17

typedef __attribute__((ext_vector_type(8))) __bf16 bf16x8;
typedef __attribute__((ext_vector_type(8))) short  short8;
typedef __attribute__((ext_vector_type(4))) float  f32x4;

__device__ __forceinline__ float gexact(float t) {
    float v = t >= 0.f ? t : 0.2f * t;
    float s = 1.f / (1.f + expf(-v));
    return expf(s);
}

__device__ __forceinline__ float tlookup(const float* __restrict__ stab, float z) {
    float zc = __builtin_amdgcn_fmed3f(z, 0.f, Z_MAX);
    return stab[(int)zc];
}

__device__ __forceinline__ float elu(float v) {
    return v > 0.f ? v : (__builtin_amdgcn_exp2f(v * LOG2E) - 1.f);
}

// ---------------- Pass A: Wh via bf16 MFMA -> B-fragments; x,y scalars via
// associativity; PLUS this block's non-atomic partial-F.  [R25 verbatim]
__global__ __launch_bounds__(256) void k_prep(const float* __restrict__ h,
                                              const float* __restrict__ W,
                                              const float* __restrict__ a,
                                              uint4* __restrict__ vfrag,
                                              float* __restrict__ ys,
                                              float* __restrict__ xs_u,
                                              float* __restrict__ ys_u,
                                              float* __restrict__ Fpart,
                                              float* __restrict__ gtab) {
    __shared__ __attribute__((aligned(16))) float  hT[64 * 68];    // padded (+4 f32)
    __shared__ __attribute__((aligned(16))) __bf16 WbT[64 * 72];   // transposed, padded
    __shared__ __attribute__((aligned(16))) __bf16 vT[64 * 74];    // Wh bf16, stride-74
    __shared__ float uv[128];                                      // u[0..64), v[64..128)
    __shared__ float gsb[GS_N];                                    // 4 KB, built locally
    __shared__ int   kuA[64];
    __shared__ float frA[64];
    int t  = threadIdx.x;
    int r0 = blockIdx.x * 64;
    int b  = blockIdx.x >> 5;
    // local gs build (4 gexact per thread)
#pragma unroll
    for (int i = t; i < GS_N; i += 256)
        gsb[i] = gexact(2.f * XG_LO + (float)i * DXG);
    const float4* hsrc = (const float4*)(h + r0 * 64);
#pragma unroll
    for (int i = 0; i < 4; i++) {
        int flat = t + i * 256;            // float4 index in 64x16
        int row = flat >> 4, c4 = flat & 15;
        float4 hv = hsrc[flat];
        float* dst = &hT[row * 68 + c4 * 4];
        dst[0] = hv.x; dst[1] = hv.y; dst[2] = hv.z; dst[3] = hv.w;
    }
#pragma unroll
    for (int i = 0; i < 4; i++) {
        int flat = t + i * 256;
        int k = flat >> 4, c4 = flat & 15;
        float4 wv = ((const float4*)W)[flat];
        WbT[(c4 * 4 + 0) * 72 + k] = (__bf16)wv.x;
        WbT[(c4 * 4 + 1) * 72 + k] = (__bf16)wv.y;
        WbT[(c4 * 4 + 2) * 72 + k] = (__bf16)wv.z;
        WbT[(c4 * 4 + 3) * 72 + k] = (__bf16)wv.w;
    }
    // u = W@a1, v = W@a2 (exact f32 from global W)
    if (t < 64) {
        float s = 0.f;
#pragma unroll 8
        for (int f = 0; f < 64; f++) s = fmaf(W[t * 64 + f], a[f], s);
        uv[t] = s;
    } else if (t < 128) {
        int k = t - 64;
        float s = 0.f;
#pragma unroll 8
        for (int f = 0; f < 64; f++) s = fmaf(W[k * 64 + f], a[64 + f], s);
        uv[64 + k] = s;
    }
    __syncthreads();
    // x,y scalars: 4 threads per row, shfl reduce; q==0 writes + ku/fr capture
    {
        int row = t >> 2, q = t & 3;
        const float* hp = &hT[row * 68 + q * 16];
        const float* up = &uv[q * 16];
        const float* vp = &uv[64 + q * 16];
        float sx = 0.f, sy = 0.f;
#pragma unroll
        for (int k2 = 0; k2 < 16; k2++) {
            float hv = hp[k2];
            sx = fmaf(hv, up[k2], sx);
            sy = fmaf(hv, vp[k2], sy);
        }
        sx += __shfl_xor(sx, 1); sx += __shfl_xor(sx, 2);
        sy += __shfl_xor(sy, 1); sy += __shfl_xor(sy, 2);
        if (q == 0) {
            int r = r0 + row;
            float xu = __builtin_amdgcn_fmed3f(sx * INV_DXG + U_BIAS, 0.f, U_MAX);
            ys[r]   = T_SCALE * sy;
            xs_u[r] = xu;
            ys_u[r] = __builtin_amdgcn_fmed3f(sy * INV_DXG + U_BIAS, 0.f, U_MAX);
            int ku  = (int)xu;
            kuA[row] = ku;
            frA[row] = xu - (float)ku;
        }
    }
    // Wh via MFMA: wave w -> 16-row tile; K=64 (2 k-steps); 4 n-tiles
    int w = t >> 6, lane = t & 63;
    int il = lane & 15, kg = lane >> 4;
    f32x4 acc0 = {0.f,0.f,0.f,0.f}, acc1 = {0.f,0.f,0.f,0.f};
    f32x4 acc2 = {0.f,0.f,0.f,0.f}, acc3 = {0.f,0.f,0.f,0.f};
#pragma unroll
    for (int ks = 0; ks < 2; ks++) {
        const float* ap = &hT[(w * 16 + il) * 68 + ks * 32 + kg * 8];
        bf16x8 af;
#pragma unroll
        for (int e = 0; e < 8; e++) af[e] = (__bf16)ap[e];
        bf16x8 b0 = *(const bf16x8*)&WbT[(0 * 16 + il) * 72 + ks * 32 + kg * 8];
        bf16x8 b1 = *(const bf16x8*)&WbT[(1 * 16 + il) * 72 + ks * 32 + kg * 8];
        bf16x8 b2 = *(const bf16x8*)&WbT[(2 * 16 + il) * 72 + ks * 32 + kg * 8];
        bf16x8 b3 = *(const bf16x8*)&WbT[(3 * 16 + il) * 72 + ks * 32 + kg * 8];
        acc0 = __builtin_amdgcn_mfma_f32_16x16x32_bf16(af, b0, acc0, 0, 0, 0);
        acc1 = __builtin_amdgcn_mfma_f32_16x16x32_bf16(af, b1, acc1, 0, 0, 0);
        acc2 = __builtin_amdgcn_mfma_f32_16x16x32_bf16(af, b2, acc2, 0, 0, 0);
        acc3 = __builtin_amdgcn_mfma_f32_16x16x32_bf16(af, b3, acc3, 0, 0, 0);
    }
    // C-layout -> LDS bf16 (col = il + nt*16, row = w*16 + kg*4 + r)
#pragma unroll
    for (int r = 0; r < 4; r++) {
        __bf16* vrow = &vT[(w * 16 + kg * 4 + r) * 74 + il];
        vrow[0]  = (__bf16)acc0[r];
        vrow[16] = (__bf16)acc1[r];
        vrow[32] = (__bf16)acc2[r];
        vrow[48] = (__bf16)acc3[r];
    }
    __syncthreads();   // covers vT, kuA/frA, gsb
    // Emit B-fragments
#pragma unroll
    for (int s = 0; s < 2; s++) {
        int oi    = t + s * 256;
        int lane2 = oi & 63;
        int nt2   = (oi >> 6) & 3;
        int ksl   = oi >> 8;
        int rbase = ksl * 32 + ((lane2 >> 4) << 3);
        int col   = nt2 * 16 + (lane2 & 15);
        short8 o;
#pragma unroll
        for (int e = 0; e < 8; e++)
            o[e] = __builtin_bit_cast(short, vT[(rbase + e) * 74 + col]);
        int ks_g = ((blockIdx.x & 31) << 1) | ksl;
        vfrag[((b * 64 + ks_g) * 4 + nt2) * 64 + lane2] = __builtin_bit_cast(uint4, o);
    }
    // Non-atomic partial F: thread t owns m = t and m = t+256.
    {
        float a0 = 0.f, a1 = 0.f;
#pragma unroll 8
        for (int r = 0; r < 64; r++) {
            int   ku = kuA[r];
            float fr = frA[r];
            float w0 = 1.f - fr;
            const float* g0 = &gsb[ku + t];
            const float* g1 = &gsb[ku + t + 256];
            a0 = fmaf(w0, g0[0], a0); a0 = fmaf(fr, g0[1], a0);
            a1 = fmaf(w0, g1[0], a1); a1 = fmaf(fr, g1[1], a1);
        }
        Fpart[blockIdx.x * MG + t]       = a0;
        Fpart[blockIdx.x * MG + t + 256] = a1;
    }
    if (blockIdx.x < 16) {
        int i = blockIdx.x * 256 + t;
        gtab[i] = gexact(T_LO + ((float)i + 0.5f) / T_SCALE);
    }
}

// ---------------- Pass B (gbuild + fused apply): block (b, ib in [0,17)) computes
// G rows [15*ib, 15*ib+16) in LDS (never global), then applies output rows whose
// G-bucket kg2 in [15*ib, 15*ib+14] — both lerp rows in-tile by construction.
__global__ __launch_bounds__(512) void k_gbuild(const float* __restrict__ ys,
                                                const float* __restrict__ ys_u,
                                                const float* __restrict__ xs_u,
                                                const float* __restrict__ Fpart,
                                                const float* __restrict__ gtab,
                                                const uint4* __restrict__ vfrag,
                                                float* __restrict__ out) {
    __shared__ float stab[NT];        // 16 KB
    __shared__ float dinvb[NN];       // 8 KB
    __shared__ float red[7][16][65];  // 29 KB; Fb then rowlist alias the front
    __shared__ __attribute__((aligned(16))) float Gl[16][64];  // 4 KB G tile
    __shared__ int cnt;
    float* Fb = &red[0][0][0];        // 512 f (prologue alias)
    int t = threadIdx.x;
    int b  = blockIdx.x / TILES;      // batch
    int ib = blockIdx.x % TILES;      // tile index [0,17)
    int mbase = ib * 15;
    {
        const float4* src = (const float4*)gtab;
        float4*       dst = (float4*)stab;
#pragma unroll
        for (int k = 0; k < NT / 4 / 512; k++) dst[t + k * 512] = src[t + k * 512];
    }
    // F = sum of this batch's 32 prep partials; thread t owns m = t.
    {
        const float* fp = Fpart + (b * 32) * MG + t;
        float s = 0.f;
#pragma unroll 8
        for (int p = 0; p < 32; p++) s += fp[p * MG];
        Fb[t] = s;
    }
    __syncthreads();
    // dinv prologue: 2048 lerp(F)+rcp, 4 per thread
#pragma unroll
    for (int i = 0; i < 4; i++) {
        int j = t + i * 512;
        float u  = ys_u[b * NN + j];
        int   k  = (int)u;
        float fr = u - (float)k;
        float d  = fmaf(Fb[k + 1] - Fb[k], fr, Fb[k]);
        dinvb[j] = __builtin_amdgcn_rcpf(d);
    }
    int kz = t >> 6, lane = t & 63;
    int il = lane & 15, kg = lane >> 4;

    float xgb = (XG_LO + (float)(mbase + il) * DXGG) * T_SCALE + Z_BIAS;
    const float* ysb = ys + b * NN;
    const uint4* vfb = vfrag + b * 16384 + lane;
    __syncthreads();

    f32x4 acc0 = {0.f,0.f,0.f,0.f}, acc1 = {0.f,0.f,0.f,0.f};
    f32x4 acc2 = {0.f,0.f,0.f,0.f}, acc3 = {0.f,0.f,0.f,0.f};

    for (int ks = kz * 8; ks < kz * 8 + 8; ks++) {
        const float* yp = ysb + ks * 32 + kg * 8;
        const float* dp = &dinvb[ks * 32 + kg * 8];
        float4 ya = *reinterpret_cast<const float4*>(yp);
        float4 yb = *reinterpret_cast<const float4*>(yp + 4);
        float wv[8];
        wv[0] = tlookup(stab, xgb + ya.x);
        wv[1] = tlookup(stab, xgb + ya.y);
        wv[2] = tlookup(stab, xgb + ya.z);
        wv[3] = tlookup(stab, xgb + ya.w);
        wv[4] = tlookup(stab, xgb + yb.x);
        wv[5] = tlookup(stab, xgb + yb.y);
        wv[6] = tlookup(stab, xgb + yb.z);
        wv[7] = tlookup(stab, xgb + yb.w);
        bf16x8 af;
#pragma unroll
        for (int e = 0; e < 8; e++) af[e] = (__bf16)(wv[e] * dp[e]);

        const uint4* vp = vfb + ks * 256;
        bf16x8 b0 = __builtin_bit_cast(bf16x8, vp[0]);
        bf16x8 b1 = __builtin_bit_cast(bf16x8, vp[64]);
        bf16x8 b2 = __builtin_bit_cast(bf16x8, vp[128]);
        bf16x8 b3 = __builtin_bit_cast(bf16x8, vp[192]);

        acc0 = __builtin_amdgcn_mfma_f32_16x16x32_bf16(af, b0, acc0, 0, 0, 0);
        acc1 = __builtin_amdgcn_mfma_f32_16x16x32_bf16(af, b1, acc1, 0, 0, 0);
        acc2 = __builtin_amdgcn_mfma_f32_16x16x32_bf16(af, b2, acc2, 0, 0, 0);
        acc3 = __builtin_amdgcn_mfma_f32_16x16x32_bf16(af, b3, acc3, 0, 0, 0);
    }

    if (kz > 0) {
#pragma unroll
        for (int r = 0; r < 4; r++) {
            float* rp = &red[kz - 1][kg * 4 + r][il];
            rp[0]  = acc0[r];
            rp[16] = acc1[r];
            rp[32] = acc2[r];
            rp[48] = acc3[r];
        }
    }
    if (t == 0) cnt = 0;
    __syncthreads();
    if (kz == 0) {
        // reduce into the LDS G tile (local rows kg*4+r, cols il+16n)
#pragma unroll
        for (int r = 0; r < 4; r++) {
            float s0 = acc0[r], s1 = acc1[r], s2 = acc2[r], s3 = acc3[r];
#pragma unroll
            for (int p = 0; p < 7; p++) {
                const float* rp = &red[p][kg * 4 + r][il];
                s0 += rp[0]; s1 += rp[16]; s2 += rp[32]; s3 += rp[48];
            }
            float* grow = &Gl[kg * 4 + r][il];
            grow[0] = s0; grow[16] = s1; grow[32] = s2; grow[48] = s3;
        }
    }
    __syncthreads();
    // Scan this batch's 2048 rows; collect those in our bucket range (alias red).
    int* rowlist = (int*)&red[0][0][0];
#pragma unroll
    for (int i = 0; i < 4; i++) {
        int row = t + i * 512;
        float u = fminf(xs_u[b * NN + row] * 0.5f, UG_MAX);
        int kg2 = (int)u;
        if (kg2 >= mbase && kg2 <= mbase + 14) {
            int slot = atomicAdd(&cnt, 1);
            rowlist[slot] = row;
        }
    }
    __syncthreads();
    // Apply: 32 rows x 16 float4-lanes per pass.
    int nrows = cnt;
    int rl = t >> 4, c4 = t & 15;
    const float4* Gl4 = (const float4*)&Gl[0][0];
    for (int base = 0; base < nrows; base += 32) {
        int idx = base + rl;
        if (idx < nrows) {
            int row = rowlist[idx];
            float u  = fminf(xs_u[b * NN + row] * 0.5f, UG_MAX);
            int   k  = (int)u;
            float fr = u - (float)k;
            int   lk = k - mbase;
            float4 g0 = Gl4[lk * 16 + c4];
            float4 g1 = Gl4[(lk + 1) * 16 + c4];
            float4 r;
            r.x = elu(fmaf(g1.x - g0.x, fr, g0.x));
            r.y = elu(fmaf(g1.y - g0.y, fr, g0.y));
            r.z = elu(fmaf(g1.z - g0.z, fr, g0.z));
            r.w = elu(fmaf(g1.w - g0.w, fr, g0.w));
            reinterpret_cast<float4*>(out)[(b * NN + row) * 16 + c4] = r;
        }
    }
}

extern "C" void kernel_launch(void* const* d_in, const int* in_sizes, int n_in,
                              void* d_out, int out_size, void* d_ws, size_t ws_size,
                              hipStream_t stream) {
    const float* h = (const float*)d_in[0];
    const float* W = (const float*)d_in[1];
    const float* a = (const float*)d_in[2];
    float* out = (float*)d_out;

    // workspace layout (floats), ~6 MB total (G buffer eliminated)
    float*  ys    = (float*)d_ws;                  // B*N (z-scaled y)
    float*  xs_u  = ys + NB * NN;                  // B*N (F-grid coords of x)
    float*  ys_u  = xs_u + NB * NN;                // B*N (F-grid coords of y)
    float*  Fpart = ys_u + NB * NN;                // 512*MG (per-block partials)
    uint4*  vfrag = (uint4*)(Fpart + (NB * NN / 64) * MG);  // B*N*64 bf16 = 4 MB
    float*  gtab  = (float*)(vfrag + NB * NN * NF / 8);     // 4096 f32

    k_prep<<<dim3(NB * NN / 64), dim3(256), 0, stream>>>(h, W, a, vfrag, ys, xs_u, ys_u, Fpart, gtab);
    k_gbuild<<<dim3(NB * TILES), dim3(512), 0, stream>>>(ys, ys_u, xs_u, Fpart, gtab, vfrag, out);
}

// Round 27
// 31.025 us; speedup vs baseline: 1.1951x; 1.1951x over previous
//
#include <hip/hip_runtime.h>
#include <hip/hip_bf16.h>
#include <math.h>

// Sizes fixed by the reference: B=16, N=2048, F_in=F_out=64.
#define NB 16
#define NN 2048
#define NF 64
#define LOG2E 1.44269504f

// g(t) nearest-neighbor table: t in [T_LO, T_HI], NT bins, value at bin midpoint.
#define NT 4096
#define T_LO (-40.0f)
#define T_HI (10.0f)
#define T_SCALE (NT / (T_HI - T_LO))         // 81.92 bins per unit t
#define Z_BIAS (-T_LO * T_SCALE)             // 3276.8
#define Z_MAX ((float)(NT - 1))

// F sampling grid: 512 points over [-96, 96), step 0.375 (division-sensitive).
#define MG 512
#define XG_LO (-96.0f)
#define DXG 0.375f
#define INV_DXG (1.0f / DXG)                 // 2.666667
#define U_BIAS (-XG_LO * INV_DXG)            // 256.0
#define U_MAX 510.999f                       // clamp so k+1 <= 511

// G sampling grid: 256 points over [-96, 96), step 0.75 (double-smoothed output).
#define MGG 256
#define DXGG 0.75f
#define UG_MAX 254.999f                      // clamp so k+1 <= 255
#define GS_N 1024

typedef __attribute__((ext_vector_type(8))) __bf16 bf16x8;
typedef __attribute__((ext_vector_type(8))) short  short8;
typedef __attribute__((ext_vector_type(4))) float  f32x4;

__device__ __forceinline__ float gexact(float t) {
    float v = t >= 0.f ? t : 0.2f * t;
    float s = 1.f / (1.f + expf(-v));
    return expf(s);
}

__device__ __forceinline__ float tlookup(const float* __restrict__ stab, float z) {
    float zc = __builtin_amdgcn_fmed3f(z, 0.f, Z_MAX);
    return stab[(int)zc];
}

__device__ __forceinline__ float elu(float v) {
    return v > 0.f ? v : (__builtin_amdgcn_exp2f(v * LOG2E) - 1.f);
}

// ---------------- Pass A: Wh via bf16 MFMA -> B-fragments; x,y scalars via
// associativity; PLUS this block's non-atomic partial-F (R12 dpart pattern).
// Blocks 0..15 build gtab.
__global__ __launch_bounds__(256) void k_prep(const float* __restrict__ h,
                                              const float* __restrict__ W,
                                              const float* __restrict__ a,
                                              uint4* __restrict__ vfrag,
                                              float* __restrict__ ys,
                                              float* __restrict__ xs_u,
                                              float* __restrict__ ys_u,
                                              float* __restrict__ Fpart,
                                              float* __restrict__ gtab) {
    __shared__ __attribute__((aligned(16))) float  hT[64 * 68];    // padded (+4 f32)
    __shared__ __attribute__((aligned(16))) __bf16 WbT[64 * 72];   // transposed, padded
    __shared__ __attribute__((aligned(16))) __bf16 vT[64 * 74];    // Wh bf16, stride-74
    __shared__ float uv[128];                                      // u[0..64), v[64..128)
    __shared__ float gsb[GS_N];                                    // 4 KB, built locally
    __shared__ int   kuA[64];
    __shared__ float frA[64];
    int t  = threadIdx.x;
    int r0 = blockIdx.x * 64;
    int b  = blockIdx.x >> 5;
    // local gs build (4 gexact per thread)
#pragma unroll
    for (int i = t; i < GS_N; i += 256)
        gsb[i] = gexact(2.f * XG_LO + (float)i * DXG);
    const float4* hsrc = (const float4*)(h + r0 * 64);
#pragma unroll
    for (int i = 0; i < 4; i++) {
        int flat = t + i * 256;            // float4 index in 64x16
        int row = flat >> 4, c4 = flat & 15;
        float4 hv = hsrc[flat];
        float* dst = &hT[row * 68 + c4 * 4];
        dst[0] = hv.x; dst[1] = hv.y; dst[2] = hv.z; dst[3] = hv.w;
    }
#pragma unroll
    for (int i = 0; i < 4; i++) {
        int flat = t + i * 256;
        int k = flat >> 4, c4 = flat & 15;
        float4 wv = ((const float4*)W)[flat];
        WbT[(c4 * 4 + 0) * 72 + k] = (__bf16)wv.x;
        WbT[(c4 * 4 + 1) * 72 + k] = (__bf16)wv.y;
        WbT[(c4 * 4 + 2) * 72 + k] = (__bf16)wv.z;
        WbT[(c4 * 4 + 3) * 72 + k] = (__bf16)wv.w;
    }
    // u = W@a1, v = W@a2 (exact f32 from global W)
    if (t < 64) {
        float s = 0.f;
#pragma unroll 8
        for (int f = 0; f < 64; f++) s = fmaf(W[t * 64 + f], a[f], s);
        uv[t] = s;
    } else if (t < 128) {
        int k = t - 64;
        float s = 0.f;
#pragma unroll 8
        for (int f = 0; f < 64; f++) s = fmaf(W[k * 64 + f], a[64 + f], s);
        uv[64 + k] = s;
    }
    __syncthreads();
    // x,y scalars: 4 threads per row, shfl reduce; q==0 writes + ku/fr capture
    {
        int row = t >> 2, q = t & 3;
        const float* hp = &hT[row * 68 + q * 16];
        const float* up = &uv[q * 16];
        const float* vp = &uv[64 + q * 16];
        float sx = 0.f, sy = 0.f;
#pragma unroll
        for (int k2 = 0; k2 < 16; k2++) {
            float hv = hp[k2];
            sx = fmaf(hv, up[k2], sx);
            sy = fmaf(hv, vp[k2], sy);
        }
        sx += __shfl_xor(sx, 1); sx += __shfl_xor(sx, 2);
        sy += __shfl_xor(sy, 1); sy += __shfl_xor(sy, 2);
        if (q == 0) {
            int r = r0 + row;
            float xu = __builtin_amdgcn_fmed3f(sx * INV_DXG + U_BIAS, 0.f, U_MAX);
            ys[r]   = T_SCALE * sy;
            xs_u[r] = xu;
            ys_u[r] = __builtin_amdgcn_fmed3f(sy * INV_DXG + U_BIAS, 0.f, U_MAX);
            int ku  = (int)xu;
            kuA[row] = ku;
            frA[row] = xu - (float)ku;
        }
    }
    // Wh via MFMA: wave w -> 16-row tile; K=64 (2 k-steps); 4 n-tiles
    int w = t >> 6, lane = t & 63;
    int il = lane & 15, kg = lane >> 4;
    f32x4 acc0 = {0.f,0.f,0.f,0.f}, acc1 = {0.f,0.f,0.f,0.f};
    f32x4 acc2 = {0.f,0.f,0.f,0.f}, acc3 = {0.f,0.f,0.f,0.f};
#pragma unroll
    for (int ks = 0; ks < 2; ks++) {
        const float* ap = &hT[(w * 16 + il) * 68 + ks * 32 + kg * 8];
        bf16x8 af;
#pragma unroll
        for (int e = 0; e < 8; e++) af[e] = (__bf16)ap[e];
        bf16x8 b0 = *(const bf16x8*)&WbT[(0 * 16 + il) * 72 + ks * 32 + kg * 8];
        bf16x8 b1 = *(const bf16x8*)&WbT[(1 * 16 + il) * 72 + ks * 32 + kg * 8];
        bf16x8 b2 = *(const bf16x8*)&WbT[(2 * 16 + il) * 72 + ks * 32 + kg * 8];
        bf16x8 b3 = *(const bf16x8*)&WbT[(3 * 16 + il) * 72 + ks * 32 + kg * 8];
        acc0 = __builtin_amdgcn_mfma_f32_16x16x32_bf16(af, b0, acc0, 0, 0, 0);
        acc1 = __builtin_amdgcn_mfma_f32_16x16x32_bf16(af, b1, acc1, 0, 0, 0);
        acc2 = __builtin_amdgcn_mfma_f32_16x16x32_bf16(af, b2, acc2, 0, 0, 0);
        acc3 = __builtin_amdgcn_mfma_f32_16x16x32_bf16(af, b3, acc3, 0, 0, 0);
    }
    // C-layout -> LDS bf16 (col = il + nt*16, row = w*16 + kg*4 + r)
#pragma unroll
    for (int r = 0; r < 4; r++) {
        __bf16* vrow = &vT[(w * 16 + kg * 4 + r) * 74 + il];
        vrow[0]  = (__bf16)acc0[r];
        vrow[16] = (__bf16)acc1[r];
        vrow[32] = (__bf16)acc2[r];
        vrow[48] = (__bf16)acc3[r];
    }
    __syncthreads();   // covers vT, kuA/frA, gsb
    // Emit B-fragments
#pragma unroll
    for (int s = 0; s < 2; s++) {
        int oi    = t + s * 256;
        int lane2 = oi & 63;
        int nt2   = (oi >> 6) & 3;
        int ksl   = oi >> 8;
        int rbase = ksl * 32 + ((lane2 >> 4) << 3);
        int col   = nt2 * 16 + (lane2 & 15);
        short8 o;
#pragma unroll
        for (int e = 0; e < 8; e++)
            o[e] = __builtin_bit_cast(short, vT[(rbase + e) * 74 + col]);
        int ks_g = ((blockIdx.x & 31) << 1) | ksl;
        vfrag[((b * 64 + ks_g) * 4 + nt2) * 64 + lane2] = __builtin_bit_cast(uint4, o);
    }
    // Non-atomic partial F: thread t owns m = t and m = t+256.
    {
        float a0 = 0.f, a1 = 0.f;
#pragma unroll 8
        for (int r = 0; r < 64; r++) {
            int   ku = kuA[r];
            float fr = frA[r];
            float w0 = 1.f - fr;
            const float* g0 = &gsb[ku + t];
            const float* g1 = &gsb[ku + t + 256];
            a0 = fmaf(w0, g0[0], a0); a0 = fmaf(fr, g0[1], a0);
            a1 = fmaf(w0, g1[0], a1); a1 = fmaf(fr, g1[1], a1);
        }
        Fpart[blockIdx.x * MG + t]       = a0;
        Fpart[blockIdx.x * MG + t + 256] = a1;
    }
    if (blockIdx.x < 16) {
        int i = blockIdx.x * 256 + t;
        gtab[i] = gexact(T_LO + ((float)i + 0.5f) / T_SCALE);
    }
}

// ---------------- Pass B: G[b][m][f] = sum_j (g(xm*+y_j)*dinv_j) * Wh[j][f]
// (MFMA, K=2048, MGG grid). Prologue sums the 32 prep partials into F.
__global__ __launch_bounds__(512) void k_gbuild(const float* __restrict__ ys,
                                                const float* __restrict__ ys_u,
                                                const float* __restrict__ Fpart,
                                                const float* __restrict__ gtab,
                                                const uint4* __restrict__ vfrag,
                                                float* __restrict__ G) {
    __shared__ float stab[NT];       // 16 KB
    __shared__ float dinvb[NN];      // 8 KB
    __shared__ float red[7][16][65]; // 29 KB; Fb aliases the front
    float* Fb = &red[0][0][0];       // 512 f
    int t = threadIdx.x;
    int b  = blockIdx.x >> 4;          // batch
    int ib = blockIdx.x & 15;          // 16 m-blocks of 16 sample rows (MGG=256)
    {
        const float4* src = (const float4*)gtab;
        float4*       dst = (float4*)stab;
#pragma unroll
        for (int k = 0; k < NT / 4 / 512; k++) dst[t + k * 512] = src[t + k * 512];
    }
    // F = sum of this batch's 32 prep partials; thread t owns m = t.
    {
        const float* fp = Fpart + (b * 32) * MG + t;
        float s = 0.f;
#pragma unroll 8
        for (int p = 0; p < 32; p++) s += fp[p * MG];
        Fb[t] = s;
    }
    __syncthreads();
    // dinv prologue: 2048 lerp(F)+rcp, 4 per thread
#pragma unroll
    for (int i = 0; i < 4; i++) {
        int j = t + i * 512;
        float u  = ys_u[b * NN + j];
        int   k  = (int)u;
        float fr = u - (float)k;
        float d  = fmaf(Fb[k + 1] - Fb[k], fr, Fb[k]);
        dinvb[j] = __builtin_amdgcn_rcpf(d);
    }
    int kz = t >> 6, lane = t & 63;
    int il = lane & 15, kg = lane >> 4;
    int mbase = ib * 16;

    float xgb = (XG_LO + (float)(mbase + il) * DXGG) * T_SCALE + Z_BIAS;
    const float* ysb = ys + b * NN;
    const uint4* vfb = vfrag + b * 16384 + lane;
    __syncthreads();

    f32x4 acc0 = {0.f,0.f,0.f,0.f}, acc1 = {0.f,0.f,0.f,0.f};
    f32x4 acc2 = {0.f,0.f,0.f,0.f}, acc3 = {0.f,0.f,0.f,0.f};

    for (int ks = kz * 8; ks < kz * 8 + 8; ks++) {
        const float* yp = ysb + ks * 32 + kg * 8;
        const float* dp = &dinvb[ks * 32 + kg * 8];
        float4 ya = *reinterpret_cast<const float4*>(yp);
        float4 yb = *reinterpret_cast<const float4*>(yp + 4);
        float wv[8];
        wv[0] = tlookup(stab, xgb + ya.x);
        wv[1] = tlookup(stab, xgb + ya.y);
        wv[2] = tlookup(stab, xgb + ya.z);
        wv[3] = tlookup(stab, xgb + ya.w);
        wv[4] = tlookup(stab, xgb + yb.x);
        wv[5] = tlookup(stab, xgb + yb.y);
        wv[6] = tlookup(stab, xgb + yb.z);
        wv[7] = tlookup(stab, xgb + yb.w);
        bf16x8 af;
#pragma unroll
        for (int e = 0; e < 8; e++) af[e] = (__bf16)(wv[e] * dp[e]);

        const uint4* vp = vfb + ks * 256;
        bf16x8 b0 = __builtin_bit_cast(bf16x8, vp[0]);
        bf16x8 b1 = __builtin_bit_cast(bf16x8, vp[64]);
        bf16x8 b2 = __builtin_bit_cast(bf16x8, vp[128]);
        bf16x8 b3 = __builtin_bit_cast(bf16x8, vp[192]);

        acc0 = __builtin_amdgcn_mfma_f32_16x16x32_bf16(af, b0, acc0, 0, 0, 0);
        acc1 = __builtin_amdgcn_mfma_f32_16x16x32_bf16(af, b1, acc1, 0, 0, 0);
        acc2 = __builtin_amdgcn_mfma_f32_16x16x32_bf16(af, b2, acc2, 0, 0, 0);
        acc3 = __builtin_amdgcn_mfma_f32_16x16x32_bf16(af, b3, acc3, 0, 0, 0);
    }

    if (kz > 0) {
#pragma unroll
        for (int r = 0; r < 4; r++) {
            float* rp = &red[kz - 1][kg * 4 + r][il];
            rp[0]  = acc0[r];
            rp[16] = acc1[r];
            rp[32] = acc2[r];
            rp[48] = acc3[r];
        }
    }
    __syncthreads();
    if (kz == 0) {
        int gbase = (b * MGG + mbase + kg * 4) * 64 + il;
#pragma unroll
        for (int r = 0; r < 4; r++) {
            float s0 = acc0[r], s1 = acc1[r], s2 = acc2[r], s3 = acc3[r];
#pragma unroll
            for (int p = 0; p < 7; p++) {
                const float* rp = &red[p][kg * 4 + r][il];
                s0 += rp[0]; s1 += rp[16]; s2 += rp[32]; s3 += rp[48];
            }
            float* grow = G + gbase + r * 64;
            grow[0] = s0; grow[16] = s1; grow[32] = s2; grow[48] = s3;
        }
    }
}

// ---------------- Pass C: out[i][f] = ELU( lerp(G_b)(x_i)[f] ), float4-vectorized.
// Block = 16 rows; thread (row-local = t>>4, c4 = t&15) handles one float4.
__global__ __launch_bounds__(256) void k_apply(const float* __restrict__ xs_u,
                                               const float* __restrict__ G,
                                               float* __restrict__ out) {
    int t   = threadIdx.x;
    int row = blockIdx.x * 16 + (t >> 4);        // [0, B*N)
    int c4  = t & 15;
    int b   = row >> 11;
    float u  = fminf(xs_u[row] * 0.5f, UG_MAX);  // F-grid -> G-grid coord
    int   k  = (int)u;
    float fr = u - (float)k;
    const float4* Gb = (const float4*)(G + (b * MGG + k) * 64);
    float4 g0 = Gb[c4];
    float4 g1 = Gb[16 + c4];
    float4 r;
    r.x = elu(fmaf(g1.x - g0.x, fr, g0.x));
    r.y = elu(fmaf(g1.y - g0.y, fr, g0.y));
    r.z = elu(fmaf(g1.z - g0.z, fr, g0.z));
    r.w = elu(fmaf(g1.w - g0.w, fr, g0.w));
    reinterpret_cast<float4*>(out)[row * 16 + c4] = r;
}

extern "C" void kernel_launch(void* const* d_in, const int* in_sizes, int n_in,
                              void* d_out, int out_size, void* d_ws, size_t ws_size,
                              hipStream_t stream) {
    const float* h = (const float*)d_in[0];
    const float* W = (const float*)d_in[1];
    const float* a = (const float*)d_in[2];
    float* out = (float*)d_out;

    // workspace layout (floats), ~7 MB total
    float*  ys    = (float*)d_ws;                  // B*N (z-scaled y)
    float*  xs_u  = ys + NB * NN;                  // B*N (F-grid coords of x)
    float*  ys_u  = xs_u + NB * NN;                // B*N (F-grid coords of y)
    float*  Fpart = ys_u + NB * NN;                // 512*MG (per-block partials)
    float*  G     = Fpart + (NB * NN / 64) * MG;   // B*MGG*64 = 262,144 f
    uint4*  vfrag = (uint4*)(G + NB * MGG * NF);   // B*N*64 bf16 = 4 MB
    float*  gtab  = (float*)(vfrag + NB * NN * NF / 8);  // 4096 f32

    k_prep<<<dim3(NB * NN / 64), dim3(256), 0, stream>>>(h, W, a, vfrag, ys, xs_u, ys_u, Fpart, gtab);
    k_gbuild<<<dim3(NB * (MGG / 16)), dim3(512), 0, stream>>>(ys, ys_u, Fpart, gtab, vfrag, G);
    k_apply<<<dim3(NB * NN / 16), dim3(256), 0, stream>>>(xs_u, G, out);
}